// Round 4
// baseline (262.032 us; speedup 1.0000x reference)
//
#include <hip/hip_runtime.h>
#include <math.h>

#define ALPHA 0.12f
#define BETA  0.88f
#define OMEGA 6.0f
#define TWO_PI 6.28318530717958647692f

constexpr int Bn   = 4;
constexpr int Tn   = 4096;
constexpr int Dn   = 2048;
constexpr int HALF = Dn / 2;      // 1024
constexpr int L    = 64;          // chunk length
constexpr int NC   = Tn / L;      // 64 chunks

typedef float fx4 __attribute__((ext_vector_type(4)));

// ---------------------------------------------------------------------------
// Single fused kernel. One block per (b, c) output chunk; 256 threads, each
// owning one pair-fx4 lane (a[p..p+3], b[p..p+3]).
//
// Carry-in via truncated warm-up: beta^64 = 2.8e-4, so the recurrence state
// entering chunk c is reproduced to ~2.8e-4 relative (then damped by
// sigmoid(gate)=0.119 in the output) by scanning chunk c-1 from zero init.
// c==0: exact (init mem_state, no warm-up). c==1: exact (init mem_state,
// warm-up chunk 0 == the true full history). c>=2: truncated, error bound
// |err_out| <= sig * beta^64 * |m| ~ 3e-5 — far below tolerance.
//
// This deletes the chunk-sum kernel, the S workspace roundtrip, and one
// launch bubble. x is read twice (warm-up + output pass) but the two touches
// of each chunk are near-simultaneous (blocks c and c+1), so the second read
// hits L2/L3 (x = 134 MB < 256 MiB Infinity Cache). Theta for the chunk's 64
// rows is computed inline into LDS, hidden under the warm-up loads.
// ---------------------------------------------------------------------------
__global__ __launch_bounds__(256) void k_fused(
        const float* __restrict__ x,
        const float* __restrict__ gate,
        const float* __restrict__ input_scale,
        const float* __restrict__ mem_state,
        const int*   __restrict__ step_idx,
        float* __restrict__ out) {
    int p4 = threadIdx.x;                 // 0..255
    int c  = blockIdx.x & (NC - 1);       // 0..63
    int b  = blockIdx.x >> 6;             // 0..3

    const float sc  = ALPHA * (*input_scale);
    const float sig = 1.0f / (1.0f + expf(-(*gate)));

    // theta table for this chunk's 64 rows → LDS (wave 0 only; latency
    // overlaps the other waves' warm-up loads)
    __shared__ float cs[L];
    __shared__ float ss[L];
    if (threadIdx.x < L) {
        int t = c * L + threadIdx.x;
        float tg = (float)(t + 1 + *step_idx);
        float theta = fmodf(OMEGA * log1pf(tg), TWO_PI);
        cs[threadIdx.x] = cosf(theta);
        ss[threadIdx.x] = sinf(theta);
    }

    // ---- carry-in reconstruction ----
    fx4 ma, mb;
    if (c < 2) {   // exact init from mem_state
        ma = ((const fx4*)mem_state)[p4];
        mb = ((const fx4*)mem_state)[p4 + HALF / 4];
    } else {       // truncated history: beta^64 ~ 2.8e-4
        ma = (fx4)(0.0f);
        mb = (fx4)(0.0f);
    }
    if (c > 0) {   // warm-up scan over chunk c-1 (no stores)
        size_t wbase = ((size_t)b * Tn + (size_t)(c - 1) * L) * Dn;
        const fx4* wa = (const fx4*)(x + wbase) + p4;
        const fx4* wb = (const fx4*)(x + wbase + HALF) + p4;
#pragma unroll 8
        for (int i = 0; i < L; ++i) {
            fx4 va = wa[(size_t)i * (Dn / 4)];
            fx4 vb = wb[(size_t)i * (Dn / 4)];
            ma = BETA * ma + sc * va;
            mb = BETA * mb + sc * vb;
        }
    }
    __syncthreads();   // cs/ss ready (all 256 threads reach this)

    // ---- output pass over chunk c ----
    size_t base = ((size_t)b * Tn + (size_t)c * L) * Dn;
    const fx4* xa = (const fx4*)(x + base) + p4;
    const fx4* xb = (const fx4*)(x + base + HALF) + p4;
    fx4* oa = (fx4*)(out + base) + p4;
    fx4* ob = (fx4*)(out + base + HALF) + p4;

#pragma unroll 4
    for (int i = 0; i < L; ++i) {
        fx4 va = xa[(size_t)i * (Dn / 4)];
        fx4 vb = xb[(size_t)i * (Dn / 4)];
        ma = BETA * ma + sc * va;
        mb = BETA * mb + sc * vb;
        float cth = cs[i];
        float sth = ss[i];
        fx4 ra = va + sig * (ma * cth - mb * sth);
        fx4 rb = vb + sig * (ma * sth + mb * cth);
        __builtin_nontemporal_store(ra, &oa[(size_t)i * (Dn / 4)]);
        __builtin_nontemporal_store(rb, &ob[(size_t)i * (Dn / 4)]);
    }
}

// ---------------------------------------------------------------------------
extern "C" void kernel_launch(void* const* d_in, const int* in_sizes, int n_in,
                              void* d_out, int out_size, void* d_ws, size_t ws_size,
                              hipStream_t stream) {
    const float* x           = (const float*)d_in[0];
    const float* gate        = (const float*)d_in[1];
    const float* input_scale = (const float*)d_in[2];
    const float* mem_state   = (const float*)d_in[3];
    const int*   step_idx    = (const int*)d_in[4];
    float* out = (float*)d_out;

    (void)d_ws; (void)ws_size;  // workspace no longer needed

    k_fused<<<Bn * NC, 256, 0, stream>>>(x, gate, input_scale, mem_state,
                                         step_idx, out);
}